// Round 1
// baseline (472.425 us; speedup 1.0000x reference)
//
#include <hip/hip_runtime.h>

// Problem constants (from reference):
//   table:   [1048576, 64] f32   (268 MB)
//   weights: [67108864, 1] f32   (268 MB)
//   idx0:    [32768, 32] i32
//   idx1:    [32768, 32] i32
//   out:     [32768, 64] f32 = mean over 32 chunks of table[idx0]*weights[idx1]
#define N_B 32768
#define N_CHUNKS 32
#define DIM 64

// Layout: 16 lanes per batch row (each lane owns one float4 of the 64-dim row),
// 256 threads/block => 16 rows/block, grid = 2048 blocks (~8 blocks/CU).
// Memory-bound gather: 16B/lane table loads are the coalescing sweet spot.
__global__ __launch_bounds__(256) void WeightedHashEmbedding_kernel(
    const float* __restrict__ table,
    const float* __restrict__ weights,
    const int*   __restrict__ idx0,
    const int*   __restrict__ idx1,
    float*       __restrict__ out)
{
    const int tid  = threadIdx.x;
    const int b    = blockIdx.x * 16 + (tid >> 4);   // batch row for this 16-lane group
    const int quad = tid & 15;                        // which float4 of the 64-dim row

    const int4* p0 = (const int4*)(idx0 + b * N_CHUNKS);
    const int4* p1 = (const int4*)(idx1 + b * N_CHUNKS);

    float4 acc = make_float4(0.f, 0.f, 0.f, 0.f);

    // unroll 2 -> ~20 outstanding loads/iter without blowing VGPR budget
    #pragma unroll 2
    for (int g = 0; g < N_CHUNKS / 4; ++g) {
        const int4 r0 = p0[g];
        const int4 r1 = p1[g];

        const float w0 = weights[r1.x];
        const float w1 = weights[r1.y];
        const float w2 = weights[r1.z];
        const float w3 = weights[r1.w];

        const float4 v0 = ((const float4*)(table + (size_t)r0.x * DIM))[quad];
        const float4 v1 = ((const float4*)(table + (size_t)r0.y * DIM))[quad];
        const float4 v2 = ((const float4*)(table + (size_t)r0.z * DIM))[quad];
        const float4 v3 = ((const float4*)(table + (size_t)r0.w * DIM))[quad];

        acc.x += v0.x * w0; acc.y += v0.y * w0; acc.z += v0.z * w0; acc.w += v0.w * w0;
        acc.x += v1.x * w1; acc.y += v1.y * w1; acc.z += v1.z * w1; acc.w += v1.w * w1;
        acc.x += v2.x * w2; acc.y += v2.y * w2; acc.z += v2.z * w2; acc.w += v2.w * w2;
        acc.x += v3.x * w3; acc.y += v3.y * w3; acc.z += v3.z * w3; acc.w += v3.w * w3;
    }

    const float inv = 1.0f / (float)N_CHUNKS;
    float4 r;
    r.x = acc.x * inv; r.y = acc.y * inv; r.z = acc.z * inv; r.w = acc.w * inv;
    ((float4*)(out + (size_t)b * DIM))[quad] = r;
}

extern "C" void kernel_launch(void* const* d_in, const int* in_sizes, int n_in,
                              void* d_out, int out_size, void* d_ws, size_t ws_size,
                              hipStream_t stream) {
    const float* table   = (const float*)d_in[0];
    const float* weights = (const float*)d_in[1];
    const int*   idx0    = (const int*)d_in[2];
    const int*   idx1    = (const int*)d_in[3];
    float*       out     = (float*)d_out;

    const int rows_per_block = 16;               // 256 threads / 16 lanes per row
    const int grid = N_B / rows_per_block;       // 2048 blocks

    WeightedHashEmbedding_kernel<<<grid, 256, 0, stream>>>(table, weights, idx0, idx1, out);
}